// Round 2
// baseline (564.438 us; speedup 1.0000x reference)
//
#include <hip/hip_runtime.h>
#include <math.h>

// GCN on MI355X. N=200000 nodes, E=6400000 edges.
// R16: R15 raised occupancy (12->21 waves/CU) but BW only 2.85->3.25 TB/s:
// VGPR dropped 52->32, per-lane in-flight lines halved -- concurrency supply
// (waves x lines/lane) was unchanged. Fix: cooperative quarter-row loads.
// The S=4 group's slot s loads quarter s (QW=PIN/4 floats) of each row ->
// 1 load & QW regs per edge per lane, so ~8 edges in flight per lane within
// the 64-VGPR/8-wave budget (4x line concurrency). Edge indices: packs of 4
// via coalesced adj[k+slot] + 3 group shuffles (sum commutative), pipelined
// one pack-pair ahead. Matmul: per-slot partials + 2-round butterfly (linear,
// same math). Slot 3's quarter is pad-zero in every layer (PIN=4QW, FIN=3QW);
// clamped W index x zero acc keeps it inert. W staged TRANSPOSED in LDS so
// the 4 slots' rows land in distinct banks.
// CSR build (R14 single-pass 2-D-hist scatter) unchanged.
// MESSAGES STAY FP32 (bf16 fails 0.21 -- R7 bisect).

static constexpr int NN = 200000;
static constexpr int NE = 6400000;
static constexpr int BK = 256;

static constexpr int SUBW  = 512;                    // nodes per sub-bin (pow2)
static constexpr int NBA   = (NN + SUBW - 1) / SUBW; // 391 sub-bins
static constexpr int CAP   = 32;                     // LDS bin capacity (recs)
static constexpr int FLUSH = 16;                     // flush granule = 64B
static constexpr int CAPB  = 18400;                  // per-bin staging cap (+15.7 sigma), %16==0
static constexpr int BKP   = 512;                    // k_part block threads
static constexpr int EPT   = 4;                      // edges per thread per chunk
static constexpr int CHUNK = BKP * EPT;              // 2048 edges per chunk
static constexpr int GPART = 768;                    // 3 blocks/CU (LDS-limited)
static constexpr int SRCSH = 13;                     // src-bucket shift (8K nodes = 512KB of p3)
static constexpr int NSB   = (NN + (1 << SRCSH) - 1) >> SRCSH;  // 25 buckets

static constexpr int S     = 4;                      // lanes per node in gathers
static constexpr int LOGS  = 2;

// ---------- pass 1: LDS-binned partition of edges into per-sub-bin staging ----------
__global__ void __launch_bounds__(BKP) k_part(const int* __restrict__ srcI,
                                              const int* __restrict__ dstI,
                                              unsigned* __restrict__ stg,
                                              int* __restrict__ gtail, int e) {
  __shared__ unsigned bin[CAP][NBA];   // [slot][bin]: random-bin writes spread banks
  __shared__ int bcnt[NBA];
  for (int t = threadIdx.x; t < NBA; t += BKP) bcnt[t] = 0;
  __syncthreads();
  int nchunks = (e + CHUNK - 1) / CHUNK;
  for (int c = blockIdx.x; c < nchunks; c += gridDim.x) {
    int base_i = c * CHUNK;
    int dv[EPT], sv[EPT];
#pragma unroll
    for (int u = 0; u < EPT; ++u) {
      int i = base_i + u * BKP + (int)threadIdx.x;
      dv[u] = (i < e) ? __builtin_nontemporal_load(dstI + i) : -1;
      sv[u] = (i < e) ? __builtin_nontemporal_load(srcI + i) : 0;
    }
#pragma unroll
    for (int u = 0; u < EPT; ++u) {
      if (dv[u] >= 0) {
        int b = dv[u] >> 9;
        unsigned rec = ((unsigned)(dv[u] & (SUBW - 1)) << 18) | (unsigned)sv[u];
        int p = atomicAdd(&bcnt[b], 1);
        if (p < CAP) {
          bin[p][b] = rec;
        } else {
          int base = atomicAdd(&gtail[b], 1);               // rare overflow fallback
          stg[(size_t)b * CAPB + base] = rec;
        }
      }
    }
    __syncthreads();
    int b2 = threadIdx.x;                                   // single-pass flush sweep
    if (b2 < NBA) {
      int c2 = bcnt[b2];
      if (c2 > CAP) c2 = CAP;
      if (c2 >= FLUSH) {
        int nfl = c2 & ~(FLUSH - 1);
        int base = atomicAdd(&gtail[b2], nfl);
        size_t o = (size_t)b2 * CAPB + base;
        for (int k = 0; k < nfl; k += 4) {
          uint4 v;
          v.x = bin[k][b2]; v.y = bin[k + 1][b2]; v.z = bin[k + 2][b2]; v.w = bin[k + 3][b2];
          *(uint4*)(stg + o + k) = v;                       // base%16==0 -> aligned
        }
        int r = c2 - nfl;
        for (int k = 0; k < r; ++k) bin[k][b2] = bin[nfl + k][b2];
        bcnt[b2] = r;
      }
    }
    __syncthreads();
  }
  int b2 = threadIdx.x;                                     // final residual flush
  if (b2 < NBA) {
    int c2 = bcnt[b2];
    if (c2 > CAP) c2 = CAP;
    if (c2 > 0) {
      int base = atomicAdd(&gtail[b2], c2);
      size_t o = (size_t)b2 * CAPB + base;
      for (int k = 0; k < c2; ++k) stg[o + k] = bin[k][b2];
    }
  }
}

// ---------- exclusive scan over sub-bin sizes (single block, 512 thr) ----------
__global__ void k_scan_sub(const int* __restrict__ gtail, int* __restrict__ sbase) {
  __shared__ int s0[512], s1[512];
  int t = threadIdx.x;
  int v = (t < NBA) ? gtail[t] : 0;
  s0[t] = v;
  __syncthreads();
  int* a = s0; int* b = s1;
  for (int off = 1; off < 512; off <<= 1) {
    int x = a[t] + ((t >= off) ? a[t - off] : 0);
    b[t] = x;
    __syncthreads();
    int* tmp = a; a = b; b = tmp;
  }
  if (t < NBA) sbase[t] = a[t] - v;  // exclusive
}

// ---------- pass 2: 2-D hist + scans + ONE ordered scatter -> rowptr, adj ----------
__global__ void __launch_bounds__(BK) k_build(const unsigned* __restrict__ stg,
                                              const int* __restrict__ gtail,
                                              const int* __restrict__ sbase,
                                              int* __restrict__ rowptr,
                                              int* __restrict__ adj) {
  __shared__ unsigned hist2[SUBW * NSB];   // 51.2 KB: [dl][sb] counts -> offsets
  __shared__ int htot[SUBW];               // per-dl total
  __shared__ int s0[SUBW], s1[SUBW];
  int b = blockIdx.x;
  int m = gtail[b]; if (m > CAPB) m = CAPB;
  size_t off = (size_t)b * CAPB;
  int base = sbase[b];
  if (b == NBA - 1 && threadIdx.x == 0) rowptr[NN] = base + m;  // dense total
  for (int t = threadIdx.x; t < SUBW * NSB; t += BK) hist2[t] = 0;
  __syncthreads();
  // read 1: 2-D histogram
  for (int k = threadIdx.x; k < m; k += BK) {
    unsigned rec = stg[off + k];
    int dl = rec >> 18;
    int sb = (int)((rec & 0x3FFFFu) >> SRCSH);
    atomicAdd(&hist2[dl * NSB + sb], 1u);
  }
  __syncthreads();
  // per-dl serial exclusive scan over sb (dl stride 25 is odd -> banks spread)
  for (int dl = threadIdx.x; dl < SUBW; dl += BK) {
    unsigned run = 0;
    for (int sb = 0; sb < NSB; ++sb) {
      unsigned c = hist2[dl * NSB + sb];
      hist2[dl * NSB + sb] = run;
      run += c;
    }
    htot[dl] = (int)run;
    s0[dl] = (int)run;
  }
  __syncthreads();
  // block inclusive scan over 512 dls (ping-pong)
  int* a = s0; int* bb = s1;
  for (int o2 = 1; o2 < SUBW; o2 <<= 1) {
    for (int t = threadIdx.x; t < SUBW; t += BK) bb[t] = a[t] + ((t >= o2) ? a[t - o2] : 0);
    __syncthreads();
    int* tmp = a; a = bb; bb = tmp;
  }
  for (int t = threadIdx.x; t < SUBW; t += BK) {
    int node = b * SUBW + t;
    int ex = a[t] - htot[t];
    if (node < NN) rowptr[node] = base + ex;
    bb[t] = ex;  // dst-base offsets live in the free scan buffer
  }
  __syncthreads();
  // read 2: single ordered scatter. pos = ex[dl] + off2d[dl][sb] + arrival.
  // adj exactly grouped by dst, exactly src-bucket-ordered within dst.
  for (int k = threadIdx.x; k < m; k += BK) {
    unsigned rec = stg[off + k];
    int dl = rec >> 18;
    unsigned src = rec & 0x3FFFFu;
    int sb = (int)(src >> SRCSH);
    int p = bb[dl] + (int)atomicAdd(&hist2[dl * NSB + sb], 1u);
    adj[base + p] = (int)src;          // single-block 64KB region, written once
  }
}

__global__ void k_zero(int* __restrict__ p, int n) {
  int i = blockIdx.x * blockDim.x + threadIdx.x;
  if (i < n) p[i] = 0;
}

// counts = rowptr diff (dense packing from counting sort)
__global__ void k_dinv(const int* __restrict__ rowptr, float* __restrict__ dinv, int n) {
  int i = blockIdx.x * blockDim.x + threadIdx.x;
  if (i < n) dinv[i] = rsqrtf(1.0f + (float)(rowptr[i + 1] - rowptr[i]));
}

// p1[i] = dinv[i] * x[i]  (3 -> padded 4 words)
__global__ void k_prep(const float* __restrict__ x, const float* __restrict__ dinv,
                       float* __restrict__ p1, int n) {
  int i = blockIdx.x * blockDim.x + threadIdx.x;
  if (i >= n) return;
  float di = dinv[i];
  float4 v;
  v.x = di * x[3 * (size_t)i];
  v.y = di * x[3 * (size_t)i + 1];
  v.z = di * x[3 * (size_t)i + 2];
  v.w = 0.f;
  *(float4*)(p1 + 4 * (size_t)i) = v;
}

// ---------- quarter-row types ----------
template <int QW> struct QT;
template <> struct QT<1> { using V = float;  };
template <> struct QT<2> { using V = float2; };
template <> struct QT<4> { using V = float4; };

__device__ inline void qacc(float* a, float v)  { a[0] += v; }
__device__ inline void qacc(float* a, float2 v) { a[0] += v.x; a[1] += v.y; }
__device__ inline void qacc(float* a, float4 v) { a[0] += v.x; a[1] += v.y; a[2] += v.z; a[3] += v.w; }

// ---------- cooperative gather: slot s accumulates quarter s of every row ----------
// Edge indices in packs of 4: one coalesced adj[k+slot] load + 3 group shuffles
// (order within the pack is a slot-dependent permutation -- sum is commutative).
// Software-pipelined one pack-pair (8 edges) ahead: next adj loads issue before
// the current rows' vmcnt waits, so the adj->row dependency never drains.
template <int PIN>
__device__ inline void gather_q(const int* __restrict__ adj, int st, int en,
                                const float* __restrict__ pinq, float* __restrict__ accq,
                                int slot) {
  constexpr int QW = PIN / 4;
  using V = typename QT<QW>::V;
  int k = st;
  if (k + 8 <= en) {
    int a0 = adj[k + slot], a1 = adj[k + 4 + slot];
    for (;;) {
      int kn = k + 8;
      bool more = (kn + 8 <= en);      // group-uniform (same i across the 4 slots)
      int a0n = 0, a1n = 0;
      if (more) { a0n = adj[kn + slot]; a1n = adj[kn + 4 + slot]; }
      int e0 = a0, e1 = __shfl_xor(a0, 1), e2 = __shfl_xor(a0, 2);
      int e3 = __shfl_xor(e1, 2);
      int f0 = a1, f1 = __shfl_xor(a1, 1), f2 = __shfl_xor(a1, 2);
      int f3 = __shfl_xor(f1, 2);
      V v0 = *(const V*)(pinq + (size_t)e0 * PIN);
      V v1 = *(const V*)(pinq + (size_t)e1 * PIN);
      V v2 = *(const V*)(pinq + (size_t)e2 * PIN);
      V v3 = *(const V*)(pinq + (size_t)e3 * PIN);
      V v4 = *(const V*)(pinq + (size_t)f0 * PIN);
      V v5 = *(const V*)(pinq + (size_t)f1 * PIN);
      V v6 = *(const V*)(pinq + (size_t)f2 * PIN);
      V v7 = *(const V*)(pinq + (size_t)f3 * PIN);
      qacc(accq, v0); qacc(accq, v1); qacc(accq, v2); qacc(accq, v3);
      qacc(accq, v4); qacc(accq, v5); qacc(accq, v6); qacc(accq, v7);
      k = kn;
      if (!more) break;
      a0 = a0n; a1 = a1n;
    }
  }
  if (k + 4 <= en) {
    int a0 = adj[k + slot];
    int e0 = a0, e1 = __shfl_xor(a0, 1), e2 = __shfl_xor(a0, 2);
    int e3 = __shfl_xor(e1, 2);
    V v0 = *(const V*)(pinq + (size_t)e0 * PIN);
    V v1 = *(const V*)(pinq + (size_t)e1 * PIN);
    V v2 = *(const V*)(pinq + (size_t)e2 * PIN);
    V v3 = *(const V*)(pinq + (size_t)e3 * PIN);
    qacc(accq, v0); qacc(accq, v1); qacc(accq, v2); qacc(accq, v3);
    k += 4;
  }
  for (; k < en; ++k) {
    V v = *(const V*)(pinq + (size_t)adj[k] * PIN);   // all 4 slots: same edge, own quarter
    qacc(accq, v);
  }
}

// ---------- fused gather: q = sum p[s]; h = dinv*(q@W)+b; act; p_out = dinv*act ----------
// MODE 0: tanh   MODE 1: l2norm then tanh
// Quarter-split: per-slot partial dot products, 2-round butterfly per output.
// Slot 3's quarter is pad-zero in every layer; clamped W index keeps it inert.
template <int PIN, int FIN, int FOUT, int POUT, int MODE>
__global__ void __launch_bounds__(BK, 8) k_gather_fused(
    const int* __restrict__ adj, const int* __restrict__ rowptr,
    const float* __restrict__ pin, const float* __restrict__ W,
    const float* __restrict__ bias, const float* __restrict__ dinv,
    float* __restrict__ pout, int n) {
  constexpr int QW = PIN / 4;
  __shared__ float sWt[FOUT * FIN];   // transposed [j][kk]: slots hit distinct banks
  __shared__ float sb[FOUT];
  for (int t = threadIdx.x; t < FIN * FOUT; t += BK) {
    int kk = t / FOUT, j = t - kk * FOUT;
    sWt[j * FIN + kk] = W[t];
  }
  if (threadIdx.x < FOUT) sb[threadIdx.x] = bias[threadIdx.x];
  __syncthreads();
  int g = blockIdx.x * blockDim.x + threadIdx.x;
  int i = g >> LOGS;
  int slot = g & (S - 1);
  if (i >= n) return;
  const float* pinq = pin + slot * QW;
  float accq[QW] = {};
  { using V = typename QT<QW>::V;
    V v = *(const V*)(pinq + (size_t)i * PIN); qacc(accq, v); }   // self-loop quarter
  gather_q<PIN>(adj, rowptr[i], rowptr[i + 1], pinq, accq, slot);
  float di = dinv[i];
  float h[FOUT];
  float ss = 0.f;
#pragma unroll
  for (int j = 0; j < FOUT; ++j) {
    float s = 0.f;
#pragma unroll
    for (int q = 0; q < QW; ++q) {
      int kk = slot * QW + q;
      if (kk > FIN - 1) kk = FIN - 1;           // slot 3 pad: accq==0 there
      s = fmaf(accq[q], sWt[j * FIN + kk], s);
    }
    s += __shfl_xor(s, 1);                      // butterfly: full dot on all slots
    s += __shfl_xor(s, 2);
    float t = fmaf(di, s, sb[j]);
    h[j] = t;
    ss += t * t;
  }
  float o[POUT];
#pragma unroll
  for (int j = 0; j < POUT; ++j) o[j] = 0.f;
  if (MODE == 0) {
#pragma unroll
    for (int j = 0; j < FOUT; ++j) o[j] = di * tanhf(h[j]);
  } else {
    float inv = 1.f / fmaxf(sqrtf(ss), 1e-12f);
#pragma unroll
    for (int j = 0; j < FOUT; ++j) o[j] = di * tanhf(h[j] * inv);
  }
  if (slot == 0) {
    float* po = pout + (size_t)i * POUT;
#pragma unroll
    for (int j = 0; j < POUT; j += 4) *(float4*)(po + j) = make_float4(o[j], o[j+1], o[j+2], o[j+3]);
  }
}

// ---------- final: gather(F_in=12) -> W3 -> l2norm -> Wc -> l2norm -> out ----------
__global__ void __launch_bounds__(BK, 8) k_gather_final(
    const int* __restrict__ adj, const int* __restrict__ rowptr,
    const float* __restrict__ pin, const float* __restrict__ W3,
    const float* __restrict__ b3, const float* __restrict__ Wc,
    const float* __restrict__ bc, const float* __restrict__ dinv,
    float* __restrict__ out, int n) {
  constexpr int PIN = 16, FIN = 12, FOUT = 24, FC = 13;
  constexpr int QW = PIN / 4;
  __shared__ float sWt[FOUT * FIN];   // transposed [j][kk]
  __shared__ float sb[FOUT];
  __shared__ float sWc[FOUT * FC];
  __shared__ float sbc[FC];
  for (int t = threadIdx.x; t < FIN * FOUT; t += BK) {
    int kk = t / FOUT, j = t - kk * FOUT;
    sWt[j * FIN + kk] = W3[t];
  }
  for (int t = threadIdx.x; t < FOUT * FC; t += BK) sWc[t] = Wc[t];
  if (threadIdx.x < FOUT) sb[threadIdx.x] = b3[threadIdx.x];
  if (threadIdx.x < FC) sbc[threadIdx.x] = bc[threadIdx.x];
  __syncthreads();
  int g = blockIdx.x * blockDim.x + threadIdx.x;
  int i = g >> LOGS;
  int slot = g & (S - 1);
  if (i >= n) return;
  const float* pinq = pin + slot * QW;
  float accq[QW] = {};
  { float4 v = *(const float4*)(pinq + (size_t)i * PIN); qacc(accq, v); }  // self
  gather_q<PIN>(adj, rowptr[i], rowptr[i + 1], pinq, accq, slot);
  float di = dinv[i];
  float h[FOUT];
  float ss = 0.f;
#pragma unroll
  for (int j = 0; j < FOUT; ++j) {
    float s = 0.f;
#pragma unroll
    for (int q = 0; q < QW; ++q) {
      int kk = slot * QW + q;
      if (kk > FIN - 1) kk = FIN - 1;           // slot 3 pad: accq==0 there
      s = fmaf(accq[q], sWt[j * FIN + kk], s);
    }
    s += __shfl_xor(s, 1);
    s += __shfl_xor(s, 2);
    float t = fmaf(di, s, sb[j]);
    h[j] = t;
    ss += t * t;
  }
  float inv = 1.f / fmaxf(sqrtf(ss), 1e-12f);   // act3 = l2norm(h)
  float v[FC];
  float ss2 = 0.f;
#pragma unroll
  for (int j = 0; j < FC; ++j) {
    float s = sbc[j];
#pragma unroll
    for (int kk = 0; kk < FOUT; ++kk) s = fmaf(h[kk] * inv, sWc[kk * FC + j], s);
    v[j] = s;
    ss2 += s * s;
  }
  float inv2 = 1.f / fmaxf(sqrtf(ss2), 1e-12f);
  if (slot == 0) {
#pragma unroll
    for (int j = 0; j < FC; ++j) out[(size_t)i * FC + j] = v[j] * inv2;
  }
}

extern "C" void kernel_launch(void* const* d_in, const int* in_sizes, int n_in,
                              void* d_out, int out_size, void* d_ws, size_t ws_size,
                              hipStream_t stream) {
  const float* x  = (const float*)d_in[0];
  const int*   ei = (const int*)d_in[1];
  const float* W1 = (const float*)d_in[2];
  const float* b1 = (const float*)d_in[3];
  const float* W2 = (const float*)d_in[4];
  const float* b2 = (const float*)d_in[5];
  const float* W3 = (const float*)d_in[6];
  const float* b3 = (const float*)d_in[7];
  const float* Wc = (const float*)d_in[8];
  const float* bc = (const float*)d_in[9];
  float* out = (float*)d_out;

  const int n = NN;
  const int e = NE;
  const int* srcI = ei;       // row 0
  const int* dstI = ei + e;   // row 1

  // Workspace (words):
  //   dinv[N] | rowptr[N+8] | gtail[512] | sbase[512] | adj[E] | pad->64B | R
  // R hosts stg[NBA*CAPB] during build, then p1[4N] | p2[8N] | p3[16N].
  // p1 is 64B-aligned; 4N*4B and 8N*4B are multiples of 64 -> p2,p3 aligned.
  // Total ~56.0 MB (R8 proved >= 76 MB safe).
  float* ws = (float*)d_ws;
  float* dinv  = ws;
  int* rowptr  = (int*)(ws + n);            // N+8 (uses N+1, padded)
  int* gtail   = rowptr + n + 8;
  int* sbase   = gtail + 512;
  int* adj     = sbase + 512;
  size_t roff = (size_t)n + (n + 8) + 512 + 512 + e;
  roff = (roff + 15) & ~(size_t)15;         // round to 16 words = 64B
  float* R     = ws + roff;
  unsigned* stg = (unsigned*)R;
  float* p1 = R;                            // 4N  (64B-aligned)
  float* p2 = R + (size_t)4 * n;            // 8N  (64B-aligned)
  float* p3 = R + (size_t)12 * n;           // 16N (64B-aligned)

  const int gn  = (n + BK - 1) / BK;
  const int gnS = (n * S + BK - 1) / BK;    // 3125 blocks

  // --- CSR build via binned counting sort, 2-D-hist-ordered scatter ---
  k_zero<<<2, BK, 0, stream>>>(gtail, 512);
  k_part<<<GPART, BKP, 0, stream>>>(srcI, dstI, stg, gtail, e);
  k_scan_sub<<<1, 512, 0, stream>>>(gtail, sbase);
  k_build<<<NBA, BK, 0, stream>>>(stg, gtail, sbase, rowptr, adj);
  k_dinv<<<gn, BK, 0, stream>>>(rowptr, dinv, n);

  // --- p1 = dinv * x ---
  k_prep<<<gn, BK, 0, stream>>>(x, dinv, p1, n);

  // --- Layer 1: gather p1 (16B rows, QW=1) -> W1 -> tanh -> p2 = dinv*act ---
  k_gather_fused<4, 3, 6, 8, 0><<<gnS, BK, 0, stream>>>(adj, rowptr, p1, W1, b1, dinv, p2, n);

  // --- Layer 2: gather p2 (32B rows, QW=2) -> W2 -> l2norm+tanh -> p3 = dinv*act ---
  k_gather_fused<8, 6, 12, 16, 1><<<gnS, BK, 0, stream>>>(adj, rowptr, p2, W2, b2, dinv, p3, n);

  // --- Layer 3 + classifier: gather p3 (64B rows, QW=4) -> W3 -> l2norm -> Wc -> l2norm ---
  k_gather_final<<<gnS, BK, 0, stream>>>(adj, rowptr, p3, W3, b3, Wc, bc, dinv, out, n);
}

// Round 3
// 468.734 us; speedup vs baseline: 1.2042x; 1.2042x over previous
//
#include <hip/hip_runtime.h>
#include <math.h>

// GCN on MI355X. N=200000 nodes, E=6400000 edges.
// R17: revert R16's cooperative-quarter gather (shuffles put lgkmcnt waits on
// the inner-loop critical path; VGPR stayed 32 -> no pipeline; 127us vs R15's
// 107us). Back to R15's slot-strided full-row gather (shuffle-free inner loop,
// butterfly once at the end), plus:
//  (a) PACKED rows: p1=3 floats (12B), p2=6 (24B), p3=12 (48B). Pad quarters
//      were 25% of gather traffic; sweep-front fetch scales with footprint
//      (R12), so FETCH should drop ~25%. All loads stay aligned: 48%16==0
//      (float4x3), 24%8==0 (float2x3), 12%4==0 (float3).
//  (b) Edge loop unroll x4 with explicit temp arrays (static idx only) and
//      adj prefetched one pack ahead; final kernel gets launch_bounds(256,6)
//      (VGPR cap 84) so the compiler can keep 4 rows in flight per lane.
// CSR build (R14 single-pass 2-D-hist scatter) unchanged.
// MESSAGES STAY FP32 (bf16 fails 0.21 -- R7 bisect).

static constexpr int NN = 200000;
static constexpr int NE = 6400000;
static constexpr int BK = 256;

static constexpr int SUBW  = 512;                    // nodes per sub-bin (pow2)
static constexpr int NBA   = (NN + SUBW - 1) / SUBW; // 391 sub-bins
static constexpr int CAP   = 32;                     // LDS bin capacity (recs)
static constexpr int FLUSH = 16;                     // flush granule = 64B
static constexpr int CAPB  = 18400;                  // per-bin staging cap (+15.7 sigma), %16==0
static constexpr int BKP   = 512;                    // k_part block threads
static constexpr int EPT   = 4;                      // edges per thread per chunk
static constexpr int CHUNK = BKP * EPT;              // 2048 edges per chunk
static constexpr int GPART = 768;                    // 3 blocks/CU (LDS-limited)
static constexpr int SRCSH = 13;                     // src-bucket shift (8K nodes)
static constexpr int NSB   = (NN + (1 << SRCSH) - 1) >> SRCSH;  // 25 buckets

static constexpr int S     = 4;                      // lanes per node in gathers
static constexpr int LOGS  = 2;

// ---------- pass 1: LDS-binned partition of edges into per-sub-bin staging ----------
__global__ void __launch_bounds__(BKP) k_part(const int* __restrict__ srcI,
                                              const int* __restrict__ dstI,
                                              unsigned* __restrict__ stg,
                                              int* __restrict__ gtail, int e) {
  __shared__ unsigned bin[CAP][NBA];   // [slot][bin]: random-bin writes spread banks
  __shared__ int bcnt[NBA];
  for (int t = threadIdx.x; t < NBA; t += BKP) bcnt[t] = 0;
  __syncthreads();
  int nchunks = (e + CHUNK - 1) / CHUNK;
  for (int c = blockIdx.x; c < nchunks; c += gridDim.x) {
    int base_i = c * CHUNK;
    int dv[EPT], sv[EPT];
#pragma unroll
    for (int u = 0; u < EPT; ++u) {
      int i = base_i + u * BKP + (int)threadIdx.x;
      dv[u] = (i < e) ? __builtin_nontemporal_load(dstI + i) : -1;
      sv[u] = (i < e) ? __builtin_nontemporal_load(srcI + i) : 0;
    }
#pragma unroll
    for (int u = 0; u < EPT; ++u) {
      if (dv[u] >= 0) {
        int b = dv[u] >> 9;
        unsigned rec = ((unsigned)(dv[u] & (SUBW - 1)) << 18) | (unsigned)sv[u];
        int p = atomicAdd(&bcnt[b], 1);
        if (p < CAP) {
          bin[p][b] = rec;
        } else {
          int base = atomicAdd(&gtail[b], 1);               // rare overflow fallback
          stg[(size_t)b * CAPB + base] = rec;
        }
      }
    }
    __syncthreads();
    int b2 = threadIdx.x;                                   // single-pass flush sweep
    if (b2 < NBA) {
      int c2 = bcnt[b2];
      if (c2 > CAP) c2 = CAP;
      if (c2 >= FLUSH) {
        int nfl = c2 & ~(FLUSH - 1);
        int base = atomicAdd(&gtail[b2], nfl);
        size_t o = (size_t)b2 * CAPB + base;
        for (int k = 0; k < nfl; k += 4) {
          uint4 v;
          v.x = bin[k][b2]; v.y = bin[k + 1][b2]; v.z = bin[k + 2][b2]; v.w = bin[k + 3][b2];
          *(uint4*)(stg + o + k) = v;                       // base%16==0 -> aligned
        }
        int r = c2 - nfl;
        for (int k = 0; k < r; ++k) bin[k][b2] = bin[nfl + k][b2];
        bcnt[b2] = r;
      }
    }
    __syncthreads();
  }
  int b2 = threadIdx.x;                                     // final residual flush
  if (b2 < NBA) {
    int c2 = bcnt[b2];
    if (c2 > CAP) c2 = CAP;
    if (c2 > 0) {
      int base = atomicAdd(&gtail[b2], c2);
      size_t o = (size_t)b2 * CAPB + base;
      for (int k = 0; k < c2; ++k) stg[o + k] = bin[k][b2];
    }
  }
}

// ---------- exclusive scan over sub-bin sizes (single block, 512 thr) ----------
__global__ void k_scan_sub(const int* __restrict__ gtail, int* __restrict__ sbase) {
  __shared__ int s0[512], s1[512];
  int t = threadIdx.x;
  int v = (t < NBA) ? gtail[t] : 0;
  s0[t] = v;
  __syncthreads();
  int* a = s0; int* b = s1;
  for (int off = 1; off < 512; off <<= 1) {
    int x = a[t] + ((t >= off) ? a[t - off] : 0);
    b[t] = x;
    __syncthreads();
    int* tmp = a; a = b; b = tmp;
  }
  if (t < NBA) sbase[t] = a[t] - v;  // exclusive
}

// ---------- pass 2: 2-D hist + scans + ONE ordered scatter -> rowptr, adj ----------
__global__ void __launch_bounds__(BK) k_build(const unsigned* __restrict__ stg,
                                              const int* __restrict__ gtail,
                                              const int* __restrict__ sbase,
                                              int* __restrict__ rowptr,
                                              int* __restrict__ adj) {
  __shared__ unsigned hist2[SUBW * NSB];   // 51.2 KB: [dl][sb] counts -> offsets
  __shared__ int htot[SUBW];               // per-dl total
  __shared__ int s0[SUBW], s1[SUBW];
  int b = blockIdx.x;
  int m = gtail[b]; if (m > CAPB) m = CAPB;
  size_t off = (size_t)b * CAPB;
  int base = sbase[b];
  if (b == NBA - 1 && threadIdx.x == 0) rowptr[NN] = base + m;  // dense total
  for (int t = threadIdx.x; t < SUBW * NSB; t += BK) hist2[t] = 0;
  __syncthreads();
  // read 1: 2-D histogram
  for (int k = threadIdx.x; k < m; k += BK) {
    unsigned rec = stg[off + k];
    int dl = rec >> 18;
    int sb = (int)((rec & 0x3FFFFu) >> SRCSH);
    atomicAdd(&hist2[dl * NSB + sb], 1u);
  }
  __syncthreads();
  // per-dl serial exclusive scan over sb (dl stride 25 is odd -> banks spread)
  for (int dl = threadIdx.x; dl < SUBW; dl += BK) {
    unsigned run = 0;
    for (int sb = 0; sb < NSB; ++sb) {
      unsigned c = hist2[dl * NSB + sb];
      hist2[dl * NSB + sb] = run;
      run += c;
    }
    htot[dl] = (int)run;
    s0[dl] = (int)run;
  }
  __syncthreads();
  // block inclusive scan over 512 dls (ping-pong)
  int* a = s0; int* bb = s1;
  for (int o2 = 1; o2 < SUBW; o2 <<= 1) {
    for (int t = threadIdx.x; t < SUBW; t += BK) bb[t] = a[t] + ((t >= o2) ? a[t - o2] : 0);
    __syncthreads();
    int* tmp = a; a = bb; bb = tmp;
  }
  for (int t = threadIdx.x; t < SUBW; t += BK) {
    int node = b * SUBW + t;
    int ex = a[t] - htot[t];
    if (node < NN) rowptr[node] = base + ex;
    bb[t] = ex;  // dst-base offsets live in the free scan buffer
  }
  __syncthreads();
  // read 2: single ordered scatter. pos = ex[dl] + off2d[dl][sb] + arrival.
  // adj exactly grouped by dst, exactly src-bucket-ordered within dst.
  for (int k = threadIdx.x; k < m; k += BK) {
    unsigned rec = stg[off + k];
    int dl = rec >> 18;
    unsigned src = rec & 0x3FFFFu;
    int sb = (int)(src >> SRCSH);
    int p = bb[dl] + (int)atomicAdd(&hist2[dl * NSB + sb], 1u);
    adj[base + p] = (int)src;          // single-block 64KB region, written once
  }
}

__global__ void k_zero(int* __restrict__ p, int n) {
  int i = blockIdx.x * blockDim.x + threadIdx.x;
  if (i < n) p[i] = 0;
}

// counts = rowptr diff (dense packing from counting sort)
__global__ void k_dinv(const int* __restrict__ rowptr, float* __restrict__ dinv, int n) {
  int i = blockIdx.x * blockDim.x + threadIdx.x;
  if (i < n) dinv[i] = rsqrtf(1.0f + (float)(rowptr[i + 1] - rowptr[i]));
}

// p1[i] = dinv[i] * x[i]  (3 floats, packed 12B rows)
__global__ void k_prep(const float* __restrict__ x, const float* __restrict__ dinv,
                       float* __restrict__ p1, int n) {
  int i = blockIdx.x * blockDim.x + threadIdx.x;
  if (i >= n) return;
  float di = dinv[i];
  float3 v;
  v.x = di * x[3 * (size_t)i];
  v.y = di * x[3 * (size_t)i + 1];
  v.z = di * x[3 * (size_t)i + 2];
  *(float3*)(p1 + 3 * (size_t)i) = v;
}

// ---------- packed-row load/accumulate (RW floats per row) ----------
template <int RW> struct RowT;
template <> struct RowT<3> {
  using T = float3;   // 12B rows: base 12i, 4B-aligned -> dwordx3
  static __device__ inline T ld(const float* __restrict__ p) { return *(const float3*)p; }
  static __device__ inline void add(float* __restrict__ a, const T& v) {
    a[0] += v.x; a[1] += v.y; a[2] += v.z;
  }
};
template <> struct RowT<6> {
  struct T { float2 a, b, c; };       // 24B rows: base 24i, 8B-aligned
  static __device__ inline T ld(const float* __restrict__ p) {
    T t; t.a = *(const float2*)p; t.b = *(const float2*)(p + 2); t.c = *(const float2*)(p + 4);
    return t;
  }
  static __device__ inline void add(float* __restrict__ a, const T& v) {
    a[0] += v.a.x; a[1] += v.a.y; a[2] += v.b.x; a[3] += v.b.y; a[4] += v.c.x; a[5] += v.c.y;
  }
};
template <> struct RowT<12> {
  struct T { float4 a, b, c; };       // 48B rows: base 48i, 16B-aligned
  static __device__ inline T ld(const float* __restrict__ p) {
    T t; t.a = *(const float4*)p; t.b = *(const float4*)(p + 4); t.c = *(const float4*)(p + 8);
    return t;
  }
  static __device__ inline void add(float* __restrict__ a, const T& v) {
    a[0] += v.a.x; a[1] += v.a.y; a[2] += v.a.z; a[3] += v.a.w;
    a[4] += v.b.x; a[5] += v.b.y; a[6] += v.b.z; a[7] += v.b.w;
    a[8] += v.c.x; a[9] += v.c.y; a[10] += v.c.z; a[11] += v.c.w;
  }
};

// ---------- slot-strided gather, unroll UN, adj prefetched one pack ahead ----------
// Lane handles edges st+slot, +S, +2S, ... (shuffle-free inner loop; the 4
// slots' partials meet in one butterfly after the loop). Temps are explicit
// arrays with static indices only (no scratch).
template <int RW, int UN>
__device__ inline void gather_p(const int* __restrict__ adj, int st, int en,
                                const float* __restrict__ pin, float* __restrict__ acc,
                                int slot) {
  using RT = RowT<RW>;
  using T = typename RT::T;
  int k = st + slot;
  if (k + (UN - 1) * S < en) {
    int a[UN];
#pragma unroll
    for (int u = 0; u < UN; ++u) a[u] = adj[k + u * S];
    for (;;) {
      int kn = k + UN * S;
      bool more = (kn + (UN - 1) * S < en);
      int b[UN];
#pragma unroll
      for (int u = 0; u < UN; ++u) b[u] = 0;
      if (more) {
#pragma unroll
        for (int u = 0; u < UN; ++u) b[u] = adj[kn + u * S];
      }
      T v[UN];
#pragma unroll
      for (int u = 0; u < UN; ++u) v[u] = RT::ld(pin + (size_t)a[u] * RW);
#pragma unroll
      for (int u = 0; u < UN; ++u) RT::add(acc, v[u]);
      k = kn;
      if (!more) break;
#pragma unroll
      for (int u = 0; u < UN; ++u) a[u] = b[u];
    }
  }
  for (; k < en; k += S) {
    T v = RT::ld(pin + (size_t)adj[k] * RW);
    RT::add(acc, v);
  }
}

// 4-lane butterfly: groups are lane-aligned (S=4 divides 64); all lanes get the sum
template <int FIN>
__device__ inline void group_reduce(float* __restrict__ acc) {
#pragma unroll
  for (int j = 0; j < FIN; ++j) {
    acc[j] += __shfl_xor(acc[j], 1);
    acc[j] += __shfl_xor(acc[j], 2);
  }
}

// ---------- fused gather: q = sum p[s]; h = dinv*(q@W)+b; act; p_out = dinv*act ----------
// MODE 0: tanh (FOUT=6, store 3x float2)   MODE 1: l2norm+tanh (FOUT=12, store 3x float4)
// RW == FIN exactly (packed rows, no pad). Slot-strided edges, butterfly at end,
// all lanes compute the epilogue redundantly, slot 0 stores.
template <int RW, int FOUT, int MODE>
__global__ void __launch_bounds__(BK, 8) k_gather_fused(
    const int* __restrict__ adj, const int* __restrict__ rowptr,
    const float* __restrict__ pin, const float* __restrict__ W,
    const float* __restrict__ bias, const float* __restrict__ dinv,
    float* __restrict__ pout, int n) {
  __shared__ float sW[RW * FOUT];
  __shared__ float sb[FOUT];
  for (int t = threadIdx.x; t < RW * FOUT; t += BK) sW[t] = W[t];
  if (threadIdx.x < FOUT) sb[threadIdx.x] = bias[threadIdx.x];
  __syncthreads();
  int g = blockIdx.x * blockDim.x + threadIdx.x;
  int i = g >> LOGS;
  int slot = g & (S - 1);
  if (i >= n) return;
  float acc[RW] = {};
  if (slot == 0) {                                  // self-loop on slot 0
    typename RowT<RW>::T v = RowT<RW>::ld(pin + (size_t)i * RW);
    RowT<RW>::add(acc, v);
  }
  gather_p<RW, 4>(adj, rowptr[i], rowptr[i + 1], pin, acc, slot);
  group_reduce<RW>(acc);
  float di = dinv[i];
  float h[FOUT];
  float ss = 0.f;
#pragma unroll
  for (int j = 0; j < FOUT; ++j) {
    float s = 0.f;
#pragma unroll
    for (int kk = 0; kk < RW; ++kk) s = fmaf(acc[kk], sW[kk * FOUT + j], s);
    float t = fmaf(di, s, sb[j]);
    h[j] = t;
    ss += t * t;
  }
  float o[FOUT];
  if (MODE == 0) {
#pragma unroll
    for (int j = 0; j < FOUT; ++j) o[j] = di * tanhf(h[j]);
  } else {
    float inv = 1.f / fmaxf(sqrtf(ss), 1e-12f);
#pragma unroll
    for (int j = 0; j < FOUT; ++j) o[j] = di * tanhf(h[j] * inv);
  }
  if (slot == 0) {
    float* po = pout + (size_t)i * FOUT;
    if (MODE == 0) {                                 // 24B rows: 3x float2 (8B-aligned)
      *(float2*)(po)     = make_float2(o[0], o[1]);
      *(float2*)(po + 2) = make_float2(o[2], o[3]);
      *(float2*)(po + 4) = make_float2(o[4], o[5]);
    } else {                                         // 48B rows: 3x float4 (16B-aligned)
      *(float4*)(po)     = make_float4(o[0], o[1], o[2], o[3]);
      *(float4*)(po + 4) = make_float4(o[4], o[5], o[6], o[7]);
      *(float4*)(po + 8) = make_float4(o[8], o[9], o[10], o[11]);
    }
  }
}

// ---------- final: gather(RW=12) -> W3 -> l2norm -> Wc -> l2norm -> out ----------
__global__ void __launch_bounds__(BK, 6) k_gather_final(
    const int* __restrict__ adj, const int* __restrict__ rowptr,
    const float* __restrict__ pin, const float* __restrict__ W3,
    const float* __restrict__ b3, const float* __restrict__ Wc,
    const float* __restrict__ bc, const float* __restrict__ dinv,
    float* __restrict__ out, int n) {
  constexpr int RW = 12, FOUT = 24, FC = 13;
  __shared__ float sW[RW * FOUT];
  __shared__ float sb[FOUT];
  __shared__ float sWc[FOUT * FC];
  __shared__ float sbc[FC];
  for (int t = threadIdx.x; t < RW * FOUT; t += BK) sW[t] = W3[t];
  for (int t = threadIdx.x; t < FOUT * FC; t += BK) sWc[t] = Wc[t];
  if (threadIdx.x < FOUT) sb[threadIdx.x] = b3[threadIdx.x];
  if (threadIdx.x < FC) sbc[threadIdx.x] = bc[threadIdx.x];
  __syncthreads();
  int g = blockIdx.x * blockDim.x + threadIdx.x;
  int i = g >> LOGS;
  int slot = g & (S - 1);
  if (i >= n) return;
  float acc[RW] = {};
  if (slot == 0) {
    RowT<RW>::T v = RowT<RW>::ld(pin + (size_t)i * RW);
    RowT<RW>::add(acc, v);
  }
  gather_p<RW, 4>(adj, rowptr[i], rowptr[i + 1], pin, acc, slot);
  group_reduce<RW>(acc);
  float di = dinv[i];
  float h[FOUT];
  float ss = 0.f;
#pragma unroll
  for (int j = 0; j < FOUT; ++j) {
    float s = 0.f;
#pragma unroll
    for (int kk = 0; kk < RW; ++kk) s = fmaf(acc[kk], sW[kk * FOUT + j], s);
    float t = fmaf(di, s, sb[j]);
    h[j] = t;
    ss += t * t;
  }
  float inv = 1.f / fmaxf(sqrtf(ss), 1e-12f);   // act3 = l2norm(h)
  float v[FC];
  float ss2 = 0.f;
#pragma unroll
  for (int j = 0; j < FC; ++j) {
    float s = sbc[j];
#pragma unroll
    for (int kk = 0; kk < FOUT; ++kk) s = fmaf(h[kk] * inv, sWc[kk * FC + j], s);
    v[j] = s;
    ss2 += s * s;
  }
  float inv2 = 1.f / fmaxf(sqrtf(ss2), 1e-12f);
  if (slot == 0) {
#pragma unroll
    for (int j = 0; j < FC; ++j) out[(size_t)i * FC + j] = v[j] * inv2;
  }
}

extern "C" void kernel_launch(void* const* d_in, const int* in_sizes, int n_in,
                              void* d_out, int out_size, void* d_ws, size_t ws_size,
                              hipStream_t stream) {
  const float* x  = (const float*)d_in[0];
  const int*   ei = (const int*)d_in[1];
  const float* W1 = (const float*)d_in[2];
  const float* b1 = (const float*)d_in[3];
  const float* W2 = (const float*)d_in[4];
  const float* b2 = (const float*)d_in[5];
  const float* W3 = (const float*)d_in[6];
  const float* b3 = (const float*)d_in[7];
  const float* Wc = (const float*)d_in[8];
  const float* bc = (const float*)d_in[9];
  float* out = (float*)d_out;

  const int n = NN;
  const int e = NE;
  const int* srcI = ei;       // row 0
  const int* dstI = ei + e;   // row 1

  // Workspace (words):
  //   dinv[N] | rowptr[N+8] | gtail[512] | sbase[512] | adj[E] | pad->64B | R
  // R hosts stg[NBA*CAPB] during build, then p1[3N] | p2[6N] | p3[12N] (packed).
  // Byte bases: p1 at 64B-aligned R; p2 at +3N*4=2.4MB (%16==0); p3 at +9N*4
  // (%16==0) -> float4 rows of p3 are 16B-aligned (48%16==0).
  // Total ~55 MB (R8 proved >= 76 MB safe).
  float* ws = (float*)d_ws;
  float* dinv  = ws;
  int* rowptr  = (int*)(ws + n);            // N+8 (uses N+1, padded)
  int* gtail   = rowptr + n + 8;
  int* sbase   = gtail + 512;
  int* adj     = sbase + 512;
  size_t roff = (size_t)n + (n + 8) + 512 + 512 + e;
  roff = (roff + 15) & ~(size_t)15;         // round to 16 words = 64B
  float* R     = ws + roff;
  unsigned* stg = (unsigned*)R;
  float* p1 = R;                            // 3N
  float* p2 = R + (size_t)3 * n;            // 6N
  float* p3 = R + (size_t)9 * n;            // 12N

  const int gn  = (n + BK - 1) / BK;
  const int gnS = (n * S + BK - 1) / BK;    // 3125 blocks

  // --- CSR build via binned counting sort, 2-D-hist-ordered scatter ---
  k_zero<<<2, BK, 0, stream>>>(gtail, 512);
  k_part<<<GPART, BKP, 0, stream>>>(srcI, dstI, stg, gtail, e);
  k_scan_sub<<<1, 512, 0, stream>>>(gtail, sbase);
  k_build<<<NBA, BK, 0, stream>>>(stg, gtail, sbase, rowptr, adj);
  k_dinv<<<gn, BK, 0, stream>>>(rowptr, dinv, n);

  // --- p1 = dinv * x (12B rows) ---
  k_prep<<<gn, BK, 0, stream>>>(x, dinv, p1, n);

  // --- Layer 1: gather p1 (12B rows) -> W1 -> tanh -> p2 = dinv*act (24B rows) ---
  k_gather_fused<3, 6, 0><<<gnS, BK, 0, stream>>>(adj, rowptr, p1, W1, b1, dinv, p2, n);

  // --- Layer 2: gather p2 (24B rows) -> W2 -> l2norm+tanh -> p3 = dinv*act (48B rows) ---
  k_gather_fused<6, 12, 1><<<gnS, BK, 0, stream>>>(adj, rowptr, p2, W2, b2, dinv, p3, n);

  // --- Layer 3 + classifier: gather p3 (48B rows) -> W3 -> l2norm -> Wc -> l2norm ---
  k_gather_final<<<gnS, BK, 0, stream>>>(adj, rowptr, p3, W3, b3, Wc, bc, dinv, out, n);
}

// Round 4
// 460.973 us; speedup vs baseline: 1.2244x; 1.0168x over previous
//
#include <hip/hip_runtime.h>
#include <math.h>

// GCN on MI355X. N=200000 nodes, E=6400000 edges.
// R18: R17 showed FETCH ~= footprint x 8 XCDs x sweep-rounds (320 MB): the
// gathers are REFETCH-bound, not supply-bound -- the loose inter-block sweep
// front re-fetches each p-row ~4x per XCD. Fix: hard-synchronize the front
// with kernel boundaries. Each gather splits into phases over src ranges
// whose slab fits per-XCD L2 (4MB): L3 -> 4 phases (2.1-2.75MB slabs),
// L2 -> 2, L1 -> 1 (2.4MB total already fits). Partial acc carried between
// phase-kernels in packed HBM buffer (butterflied into slot0, float4 IO);
// per-dst group boundaries b7/b13/b19 emitted by k_build from its bucket
// histogram (3 extra stores, zero extra passes). Slab traffic becomes
// sum(slab)x8 ~= 77MB for L3 instead of ~300.
// CSR build (R14) otherwise unchanged. MESSAGES STAY FP32 (R7: bf16 fails).

static constexpr int NN = 200000;
static constexpr int NE = 6400000;
static constexpr int BK = 256;

static constexpr int SUBW  = 512;                    // nodes per sub-bin (pow2)
static constexpr int NBA   = (NN + SUBW - 1) / SUBW; // 391 sub-bins
static constexpr int CAP   = 32;                     // LDS bin capacity (recs)
static constexpr int FLUSH = 16;                     // flush granule = 64B
static constexpr int CAPB  = 18400;                  // per-bin staging cap, %16==0
static constexpr int BKP   = 512;                    // k_part block threads
static constexpr int EPT   = 4;                      // edges per thread per chunk
static constexpr int CHUNK = BKP * EPT;              // 2048 edges per chunk
static constexpr int GPART = 768;                    // 3 blocks/CU (LDS-limited)
static constexpr int SRCSH = 13;                     // src-bucket shift (8K nodes)
static constexpr int NSB   = (NN + (1 << SRCSH) - 1) >> SRCSH;  // 25 buckets

static constexpr int S     = 4;                      // lanes per node in gathers
static constexpr int LOGS  = 2;

// ---------- pass 1: LDS-binned partition of edges into per-sub-bin staging ----------
__global__ void __launch_bounds__(BKP) k_part(const int* __restrict__ srcI,
                                              const int* __restrict__ dstI,
                                              unsigned* __restrict__ stg,
                                              int* __restrict__ gtail, int e) {
  __shared__ unsigned bin[CAP][NBA];   // [slot][bin]: random-bin writes spread banks
  __shared__ int bcnt[NBA];
  for (int t = threadIdx.x; t < NBA; t += BKP) bcnt[t] = 0;
  __syncthreads();
  int nchunks = (e + CHUNK - 1) / CHUNK;
  for (int c = blockIdx.x; c < nchunks; c += gridDim.x) {
    int base_i = c * CHUNK;
    int dv[EPT], sv[EPT];
#pragma unroll
    for (int u = 0; u < EPT; ++u) {
      int i = base_i + u * BKP + (int)threadIdx.x;
      dv[u] = (i < e) ? __builtin_nontemporal_load(dstI + i) : -1;
      sv[u] = (i < e) ? __builtin_nontemporal_load(srcI + i) : 0;
    }
#pragma unroll
    for (int u = 0; u < EPT; ++u) {
      if (dv[u] >= 0) {
        int b = dv[u] >> 9;
        unsigned rec = ((unsigned)(dv[u] & (SUBW - 1)) << 18) | (unsigned)sv[u];
        int p = atomicAdd(&bcnt[b], 1);
        if (p < CAP) {
          bin[p][b] = rec;
        } else {
          int base = atomicAdd(&gtail[b], 1);               // rare overflow fallback
          stg[(size_t)b * CAPB + base] = rec;
        }
      }
    }
    __syncthreads();
    int b2 = threadIdx.x;                                   // single-pass flush sweep
    if (b2 < NBA) {
      int c2 = bcnt[b2];
      if (c2 > CAP) c2 = CAP;
      if (c2 >= FLUSH) {
        int nfl = c2 & ~(FLUSH - 1);
        int base = atomicAdd(&gtail[b2], nfl);
        size_t o = (size_t)b2 * CAPB + base;
        for (int k = 0; k < nfl; k += 4) {
          uint4 v;
          v.x = bin[k][b2]; v.y = bin[k + 1][b2]; v.z = bin[k + 2][b2]; v.w = bin[k + 3][b2];
          *(uint4*)(stg + o + k) = v;                       // base%16==0 -> aligned
        }
        int r = c2 - nfl;
        for (int k = 0; k < r; ++k) bin[k][b2] = bin[nfl + k][b2];
        bcnt[b2] = r;
      }
    }
    __syncthreads();
  }
  int b2 = threadIdx.x;                                     // final residual flush
  if (b2 < NBA) {
    int c2 = bcnt[b2];
    if (c2 > CAP) c2 = CAP;
    if (c2 > 0) {
      int base = atomicAdd(&gtail[b2], c2);
      size_t o = (size_t)b2 * CAPB + base;
      for (int k = 0; k < c2; ++k) stg[o + k] = bin[k][b2];
    }
  }
}

// ---------- exclusive scan over sub-bin sizes (single block, 512 thr) ----------
__global__ void k_scan_sub(const int* __restrict__ gtail, int* __restrict__ sbase) {
  __shared__ int s0[512], s1[512];
  int t = threadIdx.x;
  int v = (t < NBA) ? gtail[t] : 0;
  s0[t] = v;
  __syncthreads();
  int* a = s0; int* b = s1;
  for (int off = 1; off < 512; off <<= 1) {
    int x = a[t] + ((t >= off) ? a[t - off] : 0);
    b[t] = x;
    __syncthreads();
    int* tmp = a; a = b; b = tmp;
  }
  if (t < NBA) sbase[t] = a[t] - v;  // exclusive
}

// ---------- pass 2: 2-D hist + scans + ONE ordered scatter -> rowptr, adj ----------
// Also emits per-dst group-boundary pointers b7/b13/b19 (edge index of first
// edge with src-bucket >= 7/13/19) straight from the exclusive histogram.
__global__ void __launch_bounds__(BK) k_build(const unsigned* __restrict__ stg,
                                              const int* __restrict__ gtail,
                                              const int* __restrict__ sbase,
                                              int* __restrict__ rowptr,
                                              int* __restrict__ adj,
                                              int* __restrict__ b7,
                                              int* __restrict__ b13,
                                              int* __restrict__ b19) {
  __shared__ unsigned hist2[SUBW * NSB];   // 51.2 KB: [dl][sb] counts -> offsets
  __shared__ int htot[SUBW];               // per-dl total
  __shared__ int s0[SUBW], s1[SUBW];
  int b = blockIdx.x;
  int m = gtail[b]; if (m > CAPB) m = CAPB;
  size_t off = (size_t)b * CAPB;
  int base = sbase[b];
  if (b == NBA - 1 && threadIdx.x == 0) rowptr[NN] = base + m;  // dense total
  for (int t = threadIdx.x; t < SUBW * NSB; t += BK) hist2[t] = 0;
  __syncthreads();
  // read 1: 2-D histogram
  for (int k = threadIdx.x; k < m; k += BK) {
    unsigned rec = stg[off + k];
    int dl = rec >> 18;
    int sb = (int)((rec & 0x3FFFFu) >> SRCSH);
    atomicAdd(&hist2[dl * NSB + sb], 1u);
  }
  __syncthreads();
  // per-dl serial exclusive scan over sb (dl stride 25 is odd -> banks spread)
  for (int dl = threadIdx.x; dl < SUBW; dl += BK) {
    unsigned run = 0;
    for (int sb = 0; sb < NSB; ++sb) {
      unsigned c = hist2[dl * NSB + sb];
      hist2[dl * NSB + sb] = run;
      run += c;
    }
    htot[dl] = (int)run;
    s0[dl] = (int)run;
  }
  __syncthreads();
  // block inclusive scan over 512 dls (ping-pong)
  int* a = s0; int* bb = s1;
  for (int o2 = 1; o2 < SUBW; o2 <<= 1) {
    for (int t = threadIdx.x; t < SUBW; t += BK) bb[t] = a[t] + ((t >= o2) ? a[t - o2] : 0);
    __syncthreads();
    int* tmp = a; a = bb; bb = tmp;
  }
  for (int t = threadIdx.x; t < SUBW; t += BK) {
    int node = b * SUBW + t;
    int ex = a[t] - htot[t];
    if (node < NN) {
      rowptr[node] = base + ex;
      b7[node]  = base + ex + (int)hist2[t * NSB + 7];   // hist2 is exclusive prefix here
      b13[node] = base + ex + (int)hist2[t * NSB + 13];
      b19[node] = base + ex + (int)hist2[t * NSB + 19];
    }
    bb[t] = ex;  // dst-base offsets live in the free scan buffer
  }
  __syncthreads();
  // read 2: single ordered scatter. pos = ex[dl] + off2d[dl][sb] + arrival.
  for (int k = threadIdx.x; k < m; k += BK) {
    unsigned rec = stg[off + k];
    int dl = rec >> 18;
    unsigned src = rec & 0x3FFFFu;
    int sb = (int)(src >> SRCSH);
    int p = bb[dl] + (int)atomicAdd(&hist2[dl * NSB + sb], 1u);
    adj[base + p] = (int)src;          // single-block 64KB region, written once
  }
}

__global__ void k_zero(int* __restrict__ p, int n) {
  int i = blockIdx.x * blockDim.x + threadIdx.x;
  if (i < n) p[i] = 0;
}

// counts = rowptr diff (dense packing from counting sort)
__global__ void k_dinv(const int* __restrict__ rowptr, float* __restrict__ dinv, int n) {
  int i = blockIdx.x * blockDim.x + threadIdx.x;
  if (i < n) dinv[i] = rsqrtf(1.0f + (float)(rowptr[i + 1] - rowptr[i]));
}

// p1[i] = dinv[i] * x[i]  (3 floats, packed 12B rows)
__global__ void k_prep(const float* __restrict__ x, const float* __restrict__ dinv,
                       float* __restrict__ p1, int n) {
  int i = blockIdx.x * blockDim.x + threadIdx.x;
  if (i >= n) return;
  float di = dinv[i];
  float3 v;
  v.x = di * x[3 * (size_t)i];
  v.y = di * x[3 * (size_t)i + 1];
  v.z = di * x[3 * (size_t)i + 2];
  *(float3*)(p1 + 3 * (size_t)i) = v;
}

// ---------- packed-row load/accumulate/store (RW floats per row) ----------
template <int RW> struct RowT;
template <> struct RowT<3> {
  using T = float3;   // 12B rows
  static __device__ inline T ld(const float* __restrict__ p) { return *(const float3*)p; }
  static __device__ inline void add(float* __restrict__ a, const T& v) {
    a[0] += v.x; a[1] += v.y; a[2] += v.z;
  }
  static __device__ inline void st(float* __restrict__ p, const float* __restrict__ a) {
    *(float3*)p = make_float3(a[0], a[1], a[2]);
  }
};
template <> struct RowT<6> {
  struct T { float2 a, b, c; };       // 24B rows, 8B-aligned
  static __device__ inline T ld(const float* __restrict__ p) {
    T t; t.a = *(const float2*)p; t.b = *(const float2*)(p + 2); t.c = *(const float2*)(p + 4);
    return t;
  }
  static __device__ inline void add(float* __restrict__ a, const T& v) {
    a[0] += v.a.x; a[1] += v.a.y; a[2] += v.b.x; a[3] += v.b.y; a[4] += v.c.x; a[5] += v.c.y;
  }
  static __device__ inline void st(float* __restrict__ p, const float* __restrict__ a) {
    *(float2*)(p)     = make_float2(a[0], a[1]);
    *(float2*)(p + 2) = make_float2(a[2], a[3]);
    *(float2*)(p + 4) = make_float2(a[4], a[5]);
  }
};
template <> struct RowT<12> {
  struct T { float4 a, b, c; };       // 48B rows, 16B-aligned bases
  static __device__ inline T ld(const float* __restrict__ p) {
    T t; t.a = *(const float4*)p; t.b = *(const float4*)(p + 4); t.c = *(const float4*)(p + 8);
    return t;
  }
  static __device__ inline void add(float* __restrict__ a, const T& v) {
    a[0] += v.a.x; a[1] += v.a.y; a[2] += v.a.z; a[3] += v.a.w;
    a[4] += v.b.x; a[5] += v.b.y; a[6] += v.b.z; a[7] += v.b.w;
    a[8] += v.c.x; a[9] += v.c.y; a[10] += v.c.z; a[11] += v.c.w;
  }
  static __device__ inline void st(float* __restrict__ p, const float* __restrict__ a) {
    *(float4*)(p)     = make_float4(a[0], a[1], a[2], a[3]);
    *(float4*)(p + 4) = make_float4(a[4], a[5], a[6], a[7]);
    *(float4*)(p + 8) = make_float4(a[8], a[9], a[10], a[11]);
  }
};

// ---------- slot-strided gather over [st,en), unroll UN, adj prefetch 1 ahead ----------
template <int RW, int UN>
__device__ inline void gather_p(const int* __restrict__ adj, int st, int en,
                                const float* __restrict__ pin, float* __restrict__ acc,
                                int slot) {
  using RT = RowT<RW>;
  using T = typename RT::T;
  int k = st + slot;
  if (k + (UN - 1) * S < en) {
    int a[UN];
#pragma unroll
    for (int u = 0; u < UN; ++u) a[u] = adj[k + u * S];
    for (;;) {
      int kn = k + UN * S;
      bool more = (kn + (UN - 1) * S < en);
      int b[UN];
#pragma unroll
      for (int u = 0; u < UN; ++u) b[u] = 0;
      if (more) {
#pragma unroll
        for (int u = 0; u < UN; ++u) b[u] = adj[kn + u * S];
      }
      T v[UN];
#pragma unroll
      for (int u = 0; u < UN; ++u) v[u] = RT::ld(pin + (size_t)a[u] * RW);
#pragma unroll
      for (int u = 0; u < UN; ++u) RT::add(acc, v[u]);
      k = kn;
      if (!more) break;
#pragma unroll
      for (int u = 0; u < UN; ++u) a[u] = b[u];
    }
  }
  for (; k < en; k += S) {
    T v = RT::ld(pin + (size_t)adj[k] * RW);
    RT::add(acc, v);
  }
}

// 4-lane butterfly: all lanes end with the full sum
template <int FIN>
__device__ inline void group_reduce(float* __restrict__ acc) {
#pragma unroll
  for (int j = 0; j < FIN; ++j) {
    acc[j] += __shfl_xor(acc[j], 1);
    acc[j] += __shfl_xor(acc[j], 2);
  }
}

// ---------- single-phase fused gather (layer 1 only; slab fits L2) ----------
template <int RW, int FOUT, int MODE>
__global__ void __launch_bounds__(BK, 8) k_gather_fused(
    const int* __restrict__ adj, const int* __restrict__ rowptr,
    const float* __restrict__ pin, const float* __restrict__ W,
    const float* __restrict__ bias, const float* __restrict__ dinv,
    float* __restrict__ pout, int n) {
  __shared__ float sW[RW * FOUT];
  __shared__ float sb[FOUT];
  for (int t = threadIdx.x; t < RW * FOUT; t += BK) sW[t] = W[t];
  if (threadIdx.x < FOUT) sb[threadIdx.x] = bias[threadIdx.x];
  __syncthreads();
  int g = blockIdx.x * blockDim.x + threadIdx.x;
  int i = g >> LOGS;
  int slot = g & (S - 1);
  if (i >= n) return;
  float acc[RW] = {};
  if (slot == 0) {                                  // self-loop on slot 0
    typename RowT<RW>::T v = RowT<RW>::ld(pin + (size_t)i * RW);
    RowT<RW>::add(acc, v);
  }
  gather_p<RW, 4>(adj, rowptr[i], rowptr[i + 1], pin, acc, slot);
  group_reduce<RW>(acc);
  float di = dinv[i];
  float h[FOUT];
  float ss = 0.f;
#pragma unroll
  for (int j = 0; j < FOUT; ++j) {
    float s = 0.f;
#pragma unroll
    for (int kk = 0; kk < RW; ++kk) s = fmaf(acc[kk], sW[kk * FOUT + j], s);
    float t = fmaf(di, s, sb[j]);
    h[j] = t;
    ss += t * t;
  }
  float o[FOUT];
  if (MODE == 0) {
#pragma unroll
    for (int j = 0; j < FOUT; ++j) o[j] = di * tanhf(h[j]);
  } else {
    float inv = 1.f / fmaxf(sqrtf(ss), 1e-12f);
#pragma unroll
    for (int j = 0; j < FOUT; ++j) o[j] = di * tanhf(h[j] * inv);
  }
  if (slot == 0) {
    float* po = pout + (size_t)i * FOUT;
    if (MODE == 0) {                                 // 24B rows: 3x float2
      *(float2*)(po)     = make_float2(o[0], o[1]);
      *(float2*)(po + 2) = make_float2(o[2], o[3]);
      *(float2*)(po + 4) = make_float2(o[4], o[5]);
    } else {                                         // 48B rows: 3x float4
      *(float4*)(po)     = make_float4(o[0], o[1], o[2], o[3]);
      *(float4*)(po + 4) = make_float4(o[4], o[5], o[6], o[7]);
      *(float4*)(po + 8) = make_float4(o[8], o[9], o[10], o[11]);
    }
  }
}

// ---------- phased gather: one src-range slab per kernel launch ----------
// FIRST: acc = self-loop; else acc = reload packed partial (slot 0 holds it).
// Ends by butterflying the full sum into all lanes; slot 0 stores packed.
template <int RW, bool FIRST>
__global__ void __launch_bounds__(BK, 8) k_gphase(
    const int* __restrict__ adj, const int* __restrict__ stA,
    const int* __restrict__ enB, const float* __restrict__ pin,
    float* __restrict__ accb, int n) {
  int g = blockIdx.x * blockDim.x + threadIdx.x;
  int i = g >> LOGS;
  int slot = g & (S - 1);
  if (i >= n) return;
  float acc[RW] = {};
  if (slot == 0) {
    if (FIRST) {
      typename RowT<RW>::T v = RowT<RW>::ld(pin + (size_t)i * RW);  // self-loop
      RowT<RW>::add(acc, v);
    } else {
      typename RowT<RW>::T v = RowT<RW>::ld(accb + (size_t)i * RW); // partial
      RowT<RW>::add(acc, v);
    }
  }
  gather_p<RW, 2>(adj, stA[i], enB[i], pin, acc, slot);
  group_reduce<RW>(acc);
  if (slot == 0) RowT<RW>::st(accb + (size_t)i * RW, acc);
}

// ---------- final phase: last slab + epilogue ----------
// MODE 1: l2norm+tanh -> pout (FOUT floats, 48B rows for FOUT=12)
// MODE 2: l2norm -> Wc -> l2norm -> out (13 floats)
template <int RW, int FOUT, int MODE>
__global__ void __launch_bounds__(BK, 6) k_gphase_last(
    const int* __restrict__ adj, const int* __restrict__ stA,
    const int* __restrict__ rowptr, const float* __restrict__ pin,
    const float* __restrict__ W, const float* __restrict__ bias,
    const float* __restrict__ Wc, const float* __restrict__ bc,
    const float* __restrict__ dinv, const float* __restrict__ accb,
    float* __restrict__ out, int n) {
  constexpr int FC = 13;
  __shared__ float sW[RW * FOUT];
  __shared__ float sb[FOUT];
  __shared__ float sWc[MODE == 2 ? FOUT * FC : 1];
  __shared__ float sbc[MODE == 2 ? FC : 1];
  for (int t = threadIdx.x; t < RW * FOUT; t += BK) sW[t] = W[t];
  if (threadIdx.x < FOUT) sb[threadIdx.x] = bias[threadIdx.x];
  if (MODE == 2) {
    for (int t = threadIdx.x; t < FOUT * FC; t += BK) sWc[t] = Wc[t];
    if (threadIdx.x < FC) sbc[threadIdx.x] = bc[threadIdx.x];
  }
  __syncthreads();
  int g = blockIdx.x * blockDim.x + threadIdx.x;
  int i = g >> LOGS;
  int slot = g & (S - 1);
  if (i >= n) return;
  float acc[RW] = {};
  if (slot == 0) {
    typename RowT<RW>::T v = RowT<RW>::ld(accb + (size_t)i * RW);   // partial
    RowT<RW>::add(acc, v);
  }
  gather_p<RW, 2>(adj, stA[i], rowptr[i + 1], pin, acc, slot);
  group_reduce<RW>(acc);
  float di = dinv[i];
  float h[FOUT];
  float ss = 0.f;
#pragma unroll
  for (int j = 0; j < FOUT; ++j) {
    float s = 0.f;
#pragma unroll
    for (int kk = 0; kk < RW; ++kk) s = fmaf(acc[kk], sW[kk * FOUT + j], s);
    float t = fmaf(di, s, sb[j]);
    h[j] = t;
    ss += t * t;
  }
  float inv = 1.f / fmaxf(sqrtf(ss), 1e-12f);
  if (MODE == 1) {
    float o[FOUT];
#pragma unroll
    for (int j = 0; j < FOUT; ++j) o[j] = di * tanhf(h[j] * inv);
    if (slot == 0) {
      float* po = out + (size_t)i * FOUT;                  // 48B rows (FOUT=12)
      *(float4*)(po)     = make_float4(o[0], o[1], o[2], o[3]);
      *(float4*)(po + 4) = make_float4(o[4], o[5], o[6], o[7]);
      *(float4*)(po + 8) = make_float4(o[8], o[9], o[10], o[11]);
    }
  } else {
    float v[FC];
    float ss2 = 0.f;
#pragma unroll
    for (int j = 0; j < FC; ++j) {
      float s = sbc[j];
#pragma unroll
      for (int kk = 0; kk < FOUT; ++kk) s = fmaf(h[kk] * inv, sWc[kk * FC + j], s);
      v[j] = s;
      ss2 += s * s;
    }
    float inv2 = 1.f / fmaxf(sqrtf(ss2), 1e-12f);
    if (slot == 0) {
#pragma unroll
      for (int j = 0; j < FC; ++j) out[(size_t)i * FC + j] = v[j] * inv2;
    }
  }
}

extern "C" void kernel_launch(void* const* d_in, const int* in_sizes, int n_in,
                              void* d_out, int out_size, void* d_ws, size_t ws_size,
                              hipStream_t stream) {
  const float* x  = (const float*)d_in[0];
  const int*   ei = (const int*)d_in[1];
  const float* W1 = (const float*)d_in[2];
  const float* b1 = (const float*)d_in[3];
  const float* W2 = (const float*)d_in[4];
  const float* b2 = (const float*)d_in[5];
  const float* W3 = (const float*)d_in[6];
  const float* b3 = (const float*)d_in[7];
  const float* Wc = (const float*)d_in[8];
  const float* bc = (const float*)d_in[9];
  float* out = (float*)d_out;

  const int n = NN;
  const int e = NE;
  const int* srcI = ei;       // row 0
  const int* dstI = ei + e;   // row 1

  // Workspace (words):
  //   dinv[N] | rowptr[N+8] | gtail[512] | sbase[512] | adj[E] | b7[N] | b13[N]
  //   | b19[N] | pad->64B | R
  // R hosts stg[NBA*CAPB]=7.20M words during build, then
  //   p1[3N] | p2[6N] | p3[12N] | accb[12N]  (=6.6M words) during gathers.
  // Total ~= 66 MB (R8 proved >= 76 MB safe).
  float* ws = (float*)d_ws;
  float* dinv  = ws;
  int* rowptr  = (int*)(ws + n);            // N+8 (uses N+1, padded)
  int* gtail   = rowptr + n + 8;
  int* sbase   = gtail + 512;
  int* adj     = sbase + 512;
  int* b7      = adj + e;
  int* b13     = b7 + n;
  int* b19     = b13 + n;
  size_t roff = (size_t)n + (n + 8) + 512 + 512 + e + 3 * (size_t)n;
  roff = (roff + 15) & ~(size_t)15;         // round to 16 words = 64B
  float* R     = ws + roff;
  unsigned* stg = (unsigned*)R;
  float* p1   = R;                          // 3N
  float* p2   = R + (size_t)3 * n;          // 6N
  float* p3   = R + (size_t)9 * n;          // 12N
  float* accb = R + (size_t)21 * n;         // 12N packed partials (16B-aligned)

  const int gn  = (n + BK - 1) / BK;
  const int gnS = (n * S + BK - 1) / BK;    // 3125 blocks

  // --- CSR build via binned counting sort, 2-D-hist-ordered scatter ---
  k_zero<<<2, BK, 0, stream>>>(gtail, 512);
  k_part<<<GPART, BKP, 0, stream>>>(srcI, dstI, stg, gtail, e);
  k_scan_sub<<<1, 512, 0, stream>>>(gtail, sbase);
  k_build<<<NBA, BK, 0, stream>>>(stg, gtail, sbase, rowptr, adj, b7, b13, b19);
  k_dinv<<<gn, BK, 0, stream>>>(rowptr, dinv, n);

  // --- p1 = dinv * x (12B rows) ---
  k_prep<<<gn, BK, 0, stream>>>(x, dinv, p1, n);

  // --- Layer 1 (p1 = 2.4 MB, fits per-XCD L2): single fused phase ---
  k_gather_fused<3, 6, 0><<<gnS, BK, 0, stream>>>(adj, rowptr, p1, W1, b1, dinv, p2, n);

  // --- Layer 2 (p2 = 4.8 MB): 2 phases, cut at bucket 13 ---
  k_gphase<6, true><<<gnS, BK, 0, stream>>>(adj, rowptr, b13, p2, accb, n);
  k_gphase_last<6, 12, 1><<<gnS, BK, 0, stream>>>(adj, b13, rowptr, p2, W2, b2,
                                                  Wc, bc, dinv, accb, p3, n);

  // --- Layer 3 + classifier (p3 = 9.6 MB): 4 phases, cuts at buckets 7/13/19 ---
  k_gphase<12, true><<<gnS, BK, 0, stream>>>(adj, rowptr, b7, p3, accb, n);
  k_gphase<12, false><<<gnS, BK, 0, stream>>>(adj, b7, b13, p3, accb, n);
  k_gphase<12, false><<<gnS, BK, 0, stream>>>(adj, b13, b19, p3, accb, n);
  k_gphase_last<12, 24, 2><<<gnS, BK, 0, stream>>>(adj, b19, rowptr, p3, W3, b3,
                                                   Wc, bc, dinv, accb, out, n);
}